// Round 4
// baseline (1599.748 us; speedup 1.0000x reference)
//
#include <hip/hip_runtime.h>
#include <hip/hip_bf16.h>
#include <stdint.h>

#define N_NODES 100000
#define N_EDGES 1600000
#define IN_DIM 256
#define HID 128
#define N_LAYERS 4
#define OUT_DIM 7
#define LN_EPS 1e-5f

#define SCAN_B 1024
#define SCAN_NB ((N_NODES + SCAN_B - 1) / SCAN_B)   // 98

__device__ inline float bf2f1(uint16_t u) {
    union { uint32_t i; float f; } a; a.i = ((uint32_t)u) << 16; return a.f;
}
__device__ inline uint16_t f2bf(float f) {
    union { float f; uint32_t i; } a; a.f = f;
    uint32_t lsb = (a.i >> 16) & 1u;
    a.i += 0x7fffu + lsb;          // round-to-nearest-even
    return (uint16_t)(a.i >> 16);
}

// ---------------- dtype detection ----------------
// bf16 inputs: low 16 bits of W_proj words are bf16 from U(-0.0884,0.0884)
// -> exponent in [0x60,0x7C). fp32 inputs: random mantissa bits -> ~11% hit rate.
__global__ void k_detect(const uint32_t* __restrict__ W, int* __restrict__ flag) {
    if (threadIdx.x == 0 && blockIdx.x == 0) {
        int cnt = 0;
        for (int i = 0; i < 64; i++) {
            uint32_t lo = W[i] & 0xffffu;
            uint32_t ex = (lo >> 7) & 0xff;
            if (ex >= 0x60 && ex < 0x7c) cnt++;
        }
        *flag = (cnt < 32) ? 1 : 0;   // 1 = fp32 inputs, 0 = bf16 inputs
    }
}

// ---------------- weight canonicalization (all weights -> fp32 staged) ----------------
__global__ __launch_bounds__(256) void k_cvt(const void* a0, const void* a1, const void* a2,
                                             const void* a3, const void* a4, const void* a5,
                                             const void* a6, const void* a7, const void* a8,
                                             float* __restrict__ dst, const int* __restrict__ flag) {
    int t = blockIdx.x * 256 + threadIdx.x;
    if (t >= 99720) return;
    const void* src; int i; int off;
    if      (t < 32768) { src = a0; i = t;         off = 0;     }   // W_proj 256x128
    else if (t < 32896) { src = a1; i = t - 32768; off = 32768; }   // b_proj 128
    else if (t < 33024) { src = a2; i = t - 32896; off = 32896; }   // gamma 128
    else if (t < 33152) { src = a3; i = t - 33024; off = 33024; }   // beta 128
    else if (t < 33280) { src = a4; i = t - 33152; off = 33152; }   // q_w 128
    else if (t < 33281) { src = a5; i = t - 33280; off = 33280; }   // q_b 1
    else if (t < 98817) { src = a6; i = t - 33281; off = 33296; }   // conv_w 4x128x128
    else if (t < 99713) { src = a7; i = t - 98817; off = 98832; }   // cls_w 128x7
    else                { src = a8; i = t - 99713; off = 99728; }   // cls_b 7
    float v;
    if (*flag) v = ((const float*)src)[i];
    else       v = bf2f1(((const uint16_t*)src)[i]);
    dst[off + i] = v;
}

// ---------------- graph prep ----------------

__global__ __launch_bounds__(256) void k_deg(const int* __restrict__ row, int* __restrict__ deg) {
    int e = blockIdx.x * 256 + threadIdx.x;
    if (e < N_EDGES) atomicAdd(&deg[row[e]], 1);
}

__global__ __launch_bounds__(SCAN_B) void k_scan1(const int* __restrict__ deg,
                                                  int* __restrict__ incl, int* __restrict__ bsum) {
    __shared__ int sm[SCAN_B];
    int t = threadIdx.x;
    int i = blockIdx.x * SCAN_B + t;
    int v = (i < N_NODES) ? deg[i] : 0;
    sm[t] = v;
    __syncthreads();
    for (int off = 1; off < SCAN_B; off <<= 1) {
        int add = (t >= off) ? sm[t - off] : 0;
        __syncthreads();
        sm[t] += add;
        __syncthreads();
    }
    if (i < N_NODES) incl[i] = sm[t];
    if (t == SCAN_B - 1) bsum[blockIdx.x] = sm[t];
}

__global__ __launch_bounds__(128) void k_scan2(const int* __restrict__ bsum, int* __restrict__ boff) {
    __shared__ int s[SCAN_NB];
    int t = threadIdx.x;
    if (t < SCAN_NB) s[t] = bsum[t];
    __syncthreads();
    if (t == 0) {
        int run = 0;
        for (int b = 0; b < SCAN_NB; b++) { int v = s[b]; s[b] = run; run += v; }
    }
    __syncthreads();
    if (t < SCAN_NB) boff[t] = s[t];
}

__global__ __launch_bounds__(256) void k_scan3(const int* __restrict__ deg, const int* __restrict__ incl,
                                               const int* __restrict__ boff,
                                               int* __restrict__ rp, int* __restrict__ cur,
                                               float* __restrict__ dis) {
    int i = blockIdx.x * 256 + threadIdx.x;
    if (i >= N_NODES) return;
    int d = deg[i];
    int excl = boff[i / SCAN_B] + incl[i] - d;
    rp[i]  = excl;
    cur[i] = excl;
    if (i == N_NODES - 1) rp[N_NODES] = excl + d;
    dis[i] = rsqrtf((float)(d > 0 ? d : 1));
}

__global__ __launch_bounds__(256) void k_scatter(const int* __restrict__ row, const int* __restrict__ col,
                                                 int* __restrict__ cur, int* __restrict__ csr) {
    int e = blockIdx.x * 256 + threadIdx.x;
    if (e < N_EDGES) {
        int r = row[e];
        int pos = atomicAdd(&cur[r], 1);
        csr[pos] = col[e];
    }
}

// ---------------- fused SpMM + gate + blend (fp32) ----------------
// one wave per node; lane holds cols {2*lane, 2*lane+1} as float2

__global__ __launch_bounds__(256) void k_spmm(const float* __restrict__ Hin,
                                              const float* __restrict__ H0,
                                              const int* __restrict__ rp, const int* __restrict__ csr,
                                              const float* __restrict__ dis,
                                              const float* __restrict__ qwf,
                                              const float* __restrict__ qbf,
                                              float* __restrict__ Sup) {
    int wid  = (blockIdx.x * 256 + threadIdx.x) >> 6;
    int lane = threadIdx.x & 63;
    if (wid >= N_NODES) return;

    float2 hv = ((const float2*)(Hin + (size_t)wid * 128))[lane];
    float2 qv = ((const float2*)qwf)[lane];
    float dot = hv.x * qv.x + hv.y * qv.y;
#pragma unroll
    for (int off = 32; off; off >>= 1) dot += __shfl_xor(dot, off);
    float s = 1.f / (1.f + __expf(-(dot + qbf[0] - 1.f)));

    int p0 = rp[wid], p1 = rp[wid + 1];
    float ax = 0.f, ay = 0.f;
    int p = p0;
    for (; p + 4 <= p1; p += 4) {
        int c0 = csr[p], c1 = csr[p + 1], c2 = csr[p + 2], c3 = csr[p + 3];
        float w0 = dis[c0], w1 = dis[c1], w2 = dis[c2], w3 = dis[c3];
        float2 g0 = ((const float2*)(Hin + (size_t)c0 * 128))[lane];
        float2 g1 = ((const float2*)(Hin + (size_t)c1 * 128))[lane];
        float2 g2 = ((const float2*)(Hin + (size_t)c2 * 128))[lane];
        float2 g3 = ((const float2*)(Hin + (size_t)c3 * 128))[lane];
        ax += w0 * g0.x + w1 * g1.x + w2 * g2.x + w3 * g3.x;
        ay += w0 * g0.y + w1 * g1.y + w2 * g2.y + w3 * g3.y;
    }
    for (; p < p1; p++) {
        int c = csr[p];
        float w = dis[c];
        float2 g = ((const float2*)(Hin + (size_t)c * 128))[lane];
        ax += w * g.x; ay += w * g.y;
    }
    float dr = dis[wid];
    float2 h0v = ((const float2*)(H0 + (size_t)wid * 128))[lane];
    float2 o;
    o.x = (1.f - s) * dr * ax + s * h0v.x;
    o.y = (1.f - s) * dr * ay + s * h0v.y;
    ((float2*)(Sup + (size_t)wid * 128))[lane] = o;
}

// ---------------- VALU fp32 GEMM + fused epilogue + LayerNorm (bisect: no MFMA) ----
// Block: 16 rows x 128 cols. 256 threads; thread t -> row t>>4, cols (t&15)*8..+8.
// W staged to LDS in 64-row chunks; A row-block staged to LDS once.
// MODE 0: out = LN(acc + bias)   MODE 1: out = LN(relu(theta*acc + (1-theta)*A))

template <int KD, int MODE>
__global__ __launch_bounds__(256) void k_gemm_ln(const void* __restrict__ Araw,  // [N][KD]
                                                 const float* __restrict__ Wf,   // [KD][128] fp32
                                                 const float* __restrict__ bias,
                                                 const float* __restrict__ gamma,
                                                 const float* __restrict__ beta,
                                                 float theta, const int* __restrict__ flag,
                                                 float* __restrict__ Hout) {     // [N][128] fp32
    __shared__ float As[16][KD + 8];   // +8 pad: rows land on distinct banks
    __shared__ float Ws[64][128];

    const int tid = threadIdx.x;
    const int r = tid >> 4, cg = tid & 15;
    const int j0 = cg * 8;
    const size_t row0 = (size_t)blockIdx.x * 16;

    if (MODE == 0 && *flag == 0) {
        const uint16_t* A16 = (const uint16_t*)Araw;
        for (int idx = tid; idx < 16 * KD; idx += 256) {
            int rr = idx / KD, cc = idx - rr * KD;
            As[rr][cc] = bf2f1(A16[(row0 + rr) * (size_t)KD + cc]);
        }
    } else {
        const float* A32 = (const float*)Araw;
        for (int idx = tid * 4; idx < 16 * KD; idx += 1024) {
            int rr = idx / KD, cc = idx - rr * KD;
            *(float4*)&As[rr][cc] = *(const float4*)(A32 + (row0 + rr) * (size_t)KD + cc);
        }
    }

    float acc[8];
#pragma unroll
    for (int i = 0; i < 8; i++) acc[i] = 0.f;

    for (int kh = 0; kh < KD / 64; kh++) {
        __syncthreads();   // covers As staging (kh=0) and inner-loop completion (kh>0)
        const float* Wsrc = Wf + (size_t)kh * 64 * 128;
        for (int idx = tid * 4; idx < 64 * 128; idx += 1024)
            *(float4*)&Ws[idx >> 7][idx & 127] = *(const float4*)(Wsrc + idx);
        __syncthreads();
        const int kb = kh * 64;
#pragma unroll 16
        for (int k = 0; k < 64; k++) {
            float a = As[r][kb + k];
            float4 w0 = *(const float4*)&Ws[k][j0];
            float4 w1 = *(const float4*)&Ws[k][j0 + 4];
            acc[0] += a * w0.x; acc[1] += a * w0.y; acc[2] += a * w0.z; acc[3] += a * w0.w;
            acc[4] += a * w1.x; acc[5] += a * w1.y; acc[6] += a * w1.z; acc[7] += a * w1.w;
        }
    }

    // epilogue + LayerNorm (16 lanes per row hold the full 128 cols)
    float v[8];
    float sumv = 0.f, sumsq = 0.f;
#pragma unroll
    for (int i = 0; i < 8; i++) {
        float x = acc[i];
        if (MODE == 0) {
            x += bias[j0 + i];
        } else {
            float sv = As[r][j0 + i];
            x = theta * x + (1.f - theta) * sv;
            x = x > 0.f ? x : 0.f;
        }
        v[i] = x;
        sumv += x; sumsq += x * x;
    }
    sumv  += __shfl_xor(sumv, 1);  sumv  += __shfl_xor(sumv, 2);
    sumv  += __shfl_xor(sumv, 4);  sumv  += __shfl_xor(sumv, 8);
    sumsq += __shfl_xor(sumsq, 1); sumsq += __shfl_xor(sumsq, 2);
    sumsq += __shfl_xor(sumsq, 4); sumsq += __shfl_xor(sumsq, 8);
    float mu  = sumv * (1.f / 128.f);
    float var = fmaxf(sumsq * (1.f / 128.f) - mu * mu, 0.f);
    float rs  = rsqrtf(var + LN_EPS);

    const size_t rg = row0 + r;   // grid is exact: 6250*16 == N_NODES
    float4 o0, o1;
    o0.x = gamma[j0 + 0] * (v[0] - mu) * rs + beta[j0 + 0];
    o0.y = gamma[j0 + 1] * (v[1] - mu) * rs + beta[j0 + 1];
    o0.z = gamma[j0 + 2] * (v[2] - mu) * rs + beta[j0 + 2];
    o0.w = gamma[j0 + 3] * (v[3] - mu) * rs + beta[j0 + 3];
    o1.x = gamma[j0 + 4] * (v[4] - mu) * rs + beta[j0 + 4];
    o1.y = gamma[j0 + 5] * (v[5] - mu) * rs + beta[j0 + 5];
    o1.z = gamma[j0 + 6] * (v[6] - mu) * rs + beta[j0 + 6];
    o1.w = gamma[j0 + 7] * (v[7] - mu) * rs + beta[j0 + 7];
    float* dst = Hout + rg * 128 + j0;
    *(float4*)dst = o0;
    *(float4*)(dst + 4) = o1;
}

// ---------------- classifier (fp32 in, dtype-flag out) ----------------

__global__ __launch_bounds__(256) void k_cls(const float* __restrict__ H,
                                             const float* __restrict__ Wc,
                                             const float* __restrict__ bc,
                                             const int* __restrict__ flag,
                                             void* __restrict__ out) {
    __shared__ float wS[128][8];
    int tid = threadIdx.x;
    for (int idx = tid; idx < 128 * 7; idx += 256) wS[idx / 7][idx % 7] = Wc[idx];
    __syncthreads();
    int isf32 = *flag;
    int gid = blockIdx.x * 256 + tid;
    int n = gid >> 3, j = gid & 7;
    if (n >= N_NODES || j >= OUT_DIM) return;
    const float4* hr = (const float4*)(H + (size_t)n * 128);
    float acc = bc[j];
#pragma unroll
    for (int k4 = 0; k4 < 32; k4++) {
        float4 h4 = hr[k4];
        acc += h4.x * wS[4 * k4][j]     + h4.y * wS[4 * k4 + 1][j]
             + h4.z * wS[4 * k4 + 2][j] + h4.w * wS[4 * k4 + 3][j];
    }
    size_t oi = (size_t)n * OUT_DIM + j;
    if (isf32) ((float*)out)[oi] = acc;
    else       ((uint16_t*)out)[oi] = f2bf(acc);
}

// ---------------- launch ----------------

extern "C" void kernel_launch(void* const* d_in, const int* in_sizes, int n_in,
                              void* d_out, int out_size, void* d_ws, size_t ws_size,
                              hipStream_t stream) {
    const void* x_raw = d_in[0];
    const int*  ei    = (const int*)d_in[1];
    const int* row = ei;
    const int* col = ei + N_EDGES;

    char* ws = (char*)d_ws;
    size_t off = 0;
    auto alloc = [&](size_t b) { void* p = ws + off; off = (off + b + 255) & ~(size_t)255; return p; };
    int*   flag = (int*)alloc(4);
    float* stgf = (float*)alloc((size_t)99744 * 4);
    int*   deg  = (int*)alloc((size_t)N_NODES * 4);
    int*   rp   = (int*)alloc(((size_t)N_NODES + 1) * 4);
    int*   cur  = (int*)alloc((size_t)N_NODES * 4);
    float* dis  = (float*)alloc((size_t)N_NODES * 4);
    int*   incl = (int*)alloc((size_t)N_NODES * 4);
    int*   bsum = (int*)alloc((size_t)SCAN_NB * 4);
    int*   boff = (int*)alloc((size_t)SCAN_NB * 4);
    int*   csr  = (int*)alloc((size_t)N_EDGES * 4);
    float* h0   = (float*)alloc((size_t)N_NODES * HID * 4);
    float* h    = (float*)alloc((size_t)N_NODES * HID * 4);
    float* sup  = (float*)alloc((size_t)N_NODES * HID * 4);

    // staged fp32 weight pointers
    const float* Wp  = stgf + 0;
    const float* bp  = stgf + 32768;
    const float* gm  = stgf + 32896;
    const float* bt  = stgf + 33024;
    const float* qw  = stgf + 33152;
    const float* qb  = stgf + 33280;
    const float* cw  = stgf + 33296;
    const float* clw = stgf + 98832;
    const float* clb = stgf + 99728;

    k_detect<<<1, 64, 0, stream>>>((const uint32_t*)d_in[2], flag);
    k_cvt<<<(99720 + 255) / 256, 256, 0, stream>>>(d_in[2], d_in[3], d_in[4], d_in[5], d_in[6],
                                                   d_in[7], d_in[8], d_in[9], d_in[10], stgf, flag);

    hipMemsetAsync(deg, 0, (size_t)N_NODES * 4, stream);
    k_deg<<<(N_EDGES + 255) / 256, 256, 0, stream>>>(row, deg);
    k_scan1<<<SCAN_NB, SCAN_B, 0, stream>>>(deg, incl, bsum);
    k_scan2<<<1, 128, 0, stream>>>(bsum, boff);
    k_scan3<<<(N_NODES + 255) / 256, 256, 0, stream>>>(deg, incl, boff, rp, cur, dis);
    k_scatter<<<(N_EDGES + 255) / 256, 256, 0, stream>>>(row, col, cur, csr);

    const int gemm_grid = N_NODES / 16;   // 6250, exact
    k_gemm_ln<IN_DIM, 0><<<gemm_grid, 256, 0, stream>>>(x_raw, Wp, bp, gm, bt, 0.f, flag, h0);

    const float* hin = h0;
    for (int i = 0; i < N_LAYERS; i++) {
        k_spmm<<<(N_NODES + 3) / 4, 256, 0, stream>>>(hin, h0, rp, csr, dis, qw, qb, sup);
        float theta = 0.5f / (float)(i + 1);
        k_gemm_ln<HID, 1><<<gemm_grid, 256, 0, stream>>>(sup, cw + (size_t)i * HID * HID,
                                                         nullptr, gm, bt, theta, flag, h);
        hin = h;
    }
    k_cls<<<((size_t)N_NODES * 8 + 255) / 256, 256, 0, stream>>>(h, clw, clb, flag, d_out);
}

// Round 5
// 1202.995 us; speedup vs baseline: 1.3298x; 1.3298x over previous
//
#include <hip/hip_runtime.h>
#include <hip/hip_bf16.h>
#include <stdint.h>

#define N_NODES 100000
#define N_EDGES 1600000
#define IN_DIM 256
#define HID 128
#define N_LAYERS 4
#define OUT_DIM 7
#define LN_EPS 1e-5f

#define SCAN_B 1024
#define SCAN_NB ((N_NODES + SCAN_B - 1) / SCAN_B)   // 98

__device__ inline float bf2f1(uint16_t u) {
    union { uint32_t i; float f; } a; a.i = ((uint32_t)u) << 16; return a.f;
}
__device__ inline uint16_t f2bf(float f) {
    union { float f; uint32_t i; } a; a.f = f;
    uint32_t lsb = (a.i >> 16) & 1u;
    a.i += 0x7fffu + lsb;          // round-to-nearest-even
    return (uint16_t)(a.i >> 16);
}

// ---------------- dtype detection ----------------
__global__ void k_detect(const uint32_t* __restrict__ W, int* __restrict__ flag) {
    if (threadIdx.x == 0 && blockIdx.x == 0) {
        int cnt = 0;
        for (int i = 0; i < 64; i++) {
            uint32_t lo = W[i] & 0xffffu;
            uint32_t ex = (lo >> 7) & 0xff;
            if (ex >= 0x60 && ex < 0x7c) cnt++;
        }
        *flag = (cnt < 32) ? 1 : 0;   // 1 = fp32 inputs, 0 = bf16 inputs
    }
}

// ---------------- weight canonicalization (all weights -> fp32 staged) ----------------
__global__ __launch_bounds__(256) void k_cvt(const void* a0, const void* a1, const void* a2,
                                             const void* a3, const void* a4, const void* a5,
                                             const void* a6, const void* a7, const void* a8,
                                             float* __restrict__ dst, const int* __restrict__ flag) {
    int t = blockIdx.x * 256 + threadIdx.x;
    if (t >= 99720) return;
    const void* src; int i; int off;
    if      (t < 32768) { src = a0; i = t;         off = 0;     }   // W_proj 256x128
    else if (t < 32896) { src = a1; i = t - 32768; off = 32768; }   // b_proj 128
    else if (t < 33024) { src = a2; i = t - 32896; off = 32896; }   // gamma 128
    else if (t < 33152) { src = a3; i = t - 33024; off = 33024; }   // beta 128
    else if (t < 33280) { src = a4; i = t - 33152; off = 33152; }   // q_w 128
    else if (t < 33281) { src = a5; i = t - 33280; off = 33280; }   // q_b 1
    else if (t < 98817) { src = a6; i = t - 33281; off = 33296; }   // conv_w 4x128x128
    else if (t < 99713) { src = a7; i = t - 98817; off = 98832; }   // cls_w 128x7
    else                { src = a8; i = t - 99713; off = 99728; }   // cls_b 7
    float v;
    if (*flag) v = ((const float*)src)[i];
    else       v = bf2f1(((const uint16_t*)src)[i]);
    dst[off + i] = v;
}

// ---------------- graph prep ----------------

__global__ __launch_bounds__(256) void k_deg(const int* __restrict__ row, int* __restrict__ deg) {
    int e = blockIdx.x * 256 + threadIdx.x;
    if (e < N_EDGES) atomicAdd(&deg[row[e]], 1);
}

__global__ __launch_bounds__(SCAN_B) void k_scan1(const int* __restrict__ deg,
                                                  int* __restrict__ incl, int* __restrict__ bsum) {
    __shared__ int sm[SCAN_B];
    int t = threadIdx.x;
    int i = blockIdx.x * SCAN_B + t;
    int v = (i < N_NODES) ? deg[i] : 0;
    sm[t] = v;
    __syncthreads();
    for (int off = 1; off < SCAN_B; off <<= 1) {
        int add = (t >= off) ? sm[t - off] : 0;
        __syncthreads();
        sm[t] += add;
        __syncthreads();
    }
    if (i < N_NODES) incl[i] = sm[t];
    if (t == SCAN_B - 1) bsum[blockIdx.x] = sm[t];
}

__global__ __launch_bounds__(128) void k_scan2(const int* __restrict__ bsum, int* __restrict__ boff) {
    __shared__ int s[SCAN_NB];
    int t = threadIdx.x;
    if (t < SCAN_NB) s[t] = bsum[t];
    __syncthreads();
    if (t == 0) {
        int run = 0;
        for (int b = 0; b < SCAN_NB; b++) { int v = s[b]; s[b] = run; run += v; }
    }
    __syncthreads();
    if (t < SCAN_NB) boff[t] = s[t];
}

__global__ __launch_bounds__(256) void k_scan3(const int* __restrict__ deg, const int* __restrict__ incl,
                                               const int* __restrict__ boff,
                                               int* __restrict__ rp, int* __restrict__ cur,
                                               float* __restrict__ dis) {
    int i = blockIdx.x * 256 + threadIdx.x;
    if (i >= N_NODES) return;
    int d = deg[i];
    int excl = boff[i / SCAN_B] + incl[i] - d;
    rp[i]  = excl;
    cur[i] = excl;
    if (i == N_NODES - 1) rp[N_NODES] = excl + d;
    dis[i] = rsqrtf((float)(d > 0 ? d : 1));
}

__global__ __launch_bounds__(256) void k_scatter(const int* __restrict__ row, const int* __restrict__ col,
                                                 int* __restrict__ cur, int* __restrict__ csr) {
    int e = blockIdx.x * 256 + threadIdx.x;
    if (e < N_EDGES) {
        int r = row[e];
        int pos = atomicAdd(&cur[r], 1);
        csr[pos] = col[e];
    }
}

// ---------------- fused SpMM + gate + blend (fp32) ----------------

__global__ __launch_bounds__(256) void k_spmm(const float* __restrict__ Hin,
                                              const float* __restrict__ H0,
                                              const int* __restrict__ rp, const int* __restrict__ csr,
                                              const float* __restrict__ dis,
                                              const float* __restrict__ qwf,
                                              const float* __restrict__ qbf,
                                              float* __restrict__ Sup) {
    int wid  = (blockIdx.x * 256 + threadIdx.x) >> 6;
    int lane = threadIdx.x & 63;
    if (wid >= N_NODES) return;

    float2 hv = ((const float2*)(Hin + (size_t)wid * 128))[lane];
    float2 qv = ((const float2*)qwf)[lane];
    float dot = hv.x * qv.x + hv.y * qv.y;
#pragma unroll
    for (int off = 32; off; off >>= 1) dot += __shfl_xor(dot, off);
    float s = 1.f / (1.f + __expf(-(dot + qbf[0] - 1.f)));

    int p0 = rp[wid], p1 = rp[wid + 1];
    float ax = 0.f, ay = 0.f;
    int p = p0;
    for (; p + 4 <= p1; p += 4) {
        int c0 = csr[p], c1 = csr[p + 1], c2 = csr[p + 2], c3 = csr[p + 3];
        float w0 = dis[c0], w1 = dis[c1], w2 = dis[c2], w3 = dis[c3];
        float2 g0 = ((const float2*)(Hin + (size_t)c0 * 128))[lane];
        float2 g1 = ((const float2*)(Hin + (size_t)c1 * 128))[lane];
        float2 g2 = ((const float2*)(Hin + (size_t)c2 * 128))[lane];
        float2 g3 = ((const float2*)(Hin + (size_t)c3 * 128))[lane];
        ax += w0 * g0.x + w1 * g1.x + w2 * g2.x + w3 * g3.x;
        ay += w0 * g0.y + w1 * g1.y + w2 * g2.y + w3 * g3.y;
    }
    for (; p < p1; p++) {
        int c = csr[p];
        float w = dis[c];
        float2 g = ((const float2*)(Hin + (size_t)c * 128))[lane];
        ax += w * g.x; ay += w * g.y;
    }
    float dr = dis[wid];
    float2 h0v = ((const float2*)(H0 + (size_t)wid * 128))[lane];
    float2 o;
    o.x = (1.f - s) * dr * ax + s * h0v.x;
    o.y = (1.f - s) * dr * ay + s * h0v.y;
    ((float2*)(Sup + (size_t)wid * 128))[lane] = o;
}

// ---------------- VALU fp32 GEMM, register-blocked 4x8, + fused LN ----------------
// Block = 64 rows x 128 cols, 256 threads.
// Thread t: rows rr*4..rr*4+4 (rr=t>>4), cols {cg*4..+4} U {64+cg*4..+4} (cg=t&15).
// Cols split at +64 so 16 lanes' float4 LDS reads span all 32 banks (2-way = free).
// W staged in 64-k LDS chunks; A staged fp32-converted in 64x64 LDS chunks.
// MODE 0: out = LN(acc + bias)   MODE 1: out = LN(relu(theta*acc + (1-theta)*A))

template <int KD, int MODE>
__global__ __launch_bounds__(256) void k_gemm_ln(const void* __restrict__ Araw,  // [N][KD]
                                                 const float* __restrict__ Wf,   // [KD][128] fp32
                                                 const float* __restrict__ bias,
                                                 const float* __restrict__ gamma,
                                                 const float* __restrict__ beta,
                                                 float theta, const int* __restrict__ flag,
                                                 float* __restrict__ Hout) {     // [N][128] fp32
    __shared__ float Ws[64][128];   // 32 KiB
    __shared__ float As[64][68];    // 17 KiB (pad 4: rr groups land 2-way)

    const int tid = threadIdx.x;
    const int cg = tid & 15, rr = tid >> 4;
    const int j0 = cg * 4;
    const size_t row0base = (size_t)blockIdx.x * 64;
    const size_t row0 = row0base + (size_t)rr * 4;
    const int f32in = (MODE == 1) ? 1 : *flag;

    float acc[4][8];
#pragma unroll
    for (int i = 0; i < 4; i++)
#pragma unroll
        for (int c = 0; c < 8; c++) acc[i][c] = 0.f;

    for (int kh = 0; kh < KD / 64; kh++) {
        __syncthreads();   // protect LDS from previous chunk's readers
        // stage W chunk [kh*64, kh*64+64) x 128
        const float* Wsrc = Wf + (size_t)kh * 64 * 128;
        for (int idx = tid * 4; idx < 64 * 128; idx += 1024)
            *(float4*)&Ws[idx >> 7][idx & 127] = *(const float4*)(Wsrc + idx);
        // stage A chunk 64 rows x 64 cols, converted to fp32
        if (f32in) {
            const float* A32 = (const float*)Araw;
#pragma unroll
            for (int qq = 0; qq < 4; qq++) {
                int idx4 = tid + qq * 256;
                int r = idx4 >> 4, c4 = idx4 & 15;
                size_t rg = row0base + r; if (rg >= N_NODES) rg = N_NODES - 1;
                *(float4*)&As[r][c4 * 4] = *(const float4*)(A32 + rg * KD + kh * 64 + c4 * 4);
            }
        } else {
            const uint16_t* A16 = (const uint16_t*)Araw;
#pragma unroll
            for (int qq = 0; qq < 4; qq++) {
                int idx4 = tid + qq * 256;
                int r = idx4 >> 4, c4 = idx4 & 15;
                size_t rg = row0base + r; if (rg >= N_NODES) rg = N_NODES - 1;
                const uint16_t* p = A16 + rg * KD + kh * 64 + c4 * 4;
                float4 f;
                f.x = bf2f1(p[0]); f.y = bf2f1(p[1]); f.z = bf2f1(p[2]); f.w = bf2f1(p[3]);
                *(float4*)&As[r][c4 * 4] = f;
            }
        }
        __syncthreads();

#pragma unroll 4
        for (int k4 = 0; k4 < 16; k4++) {
            float4 av[4];
#pragma unroll
            for (int i = 0; i < 4; i++) av[i] = *(const float4*)&As[rr * 4 + i][k4 * 4];
#pragma unroll
            for (int kk = 0; kk < 4; kk++) {
                int k = k4 * 4 + kk;
                float4 w0 = *(const float4*)&Ws[k][j0];
                float4 w1 = *(const float4*)&Ws[k][j0 + 64];
#pragma unroll
                for (int i = 0; i < 4; i++) {
                    float a = (kk == 0) ? av[i].x : (kk == 1) ? av[i].y
                            : (kk == 2) ? av[i].z : av[i].w;
                    acc[i][0] += a * w0.x; acc[i][1] += a * w0.y;
                    acc[i][2] += a * w0.z; acc[i][3] += a * w0.w;
                    acc[i][4] += a * w1.x; acc[i][5] += a * w1.y;
                    acc[i][6] += a * w1.z; acc[i][7] += a * w1.w;
                }
            }
        }
    }

    // epilogue params for this thread's 8 cols
    float4 gm0 = *(const float4*)(gamma + j0), gm1 = *(const float4*)(gamma + j0 + 64);
    float4 be0 = *(const float4*)(beta  + j0), be1 = *(const float4*)(beta  + j0 + 64);
    float4 bi0 = {0,0,0,0}, bi1 = {0,0,0,0};
    if (MODE == 0) { bi0 = *(const float4*)(bias + j0); bi1 = *(const float4*)(bias + j0 + 64); }

#pragma unroll
    for (int i = 0; i < 4; i++) {
        size_t rg = row0 + i;
        size_t rc = (rg < N_NODES) ? rg : (N_NODES - 1);
        float v[8];
        if (MODE == 0) {
            v[0] = acc[i][0] + bi0.x; v[1] = acc[i][1] + bi0.y;
            v[2] = acc[i][2] + bi0.z; v[3] = acc[i][3] + bi0.w;
            v[4] = acc[i][4] + bi1.x; v[5] = acc[i][5] + bi1.y;
            v[6] = acc[i][6] + bi1.z; v[7] = acc[i][7] + bi1.w;
        } else {
            const float* A32 = (const float*)Araw;
            float4 s0 = *(const float4*)(A32 + rc * KD + j0);
            float4 s1 = *(const float4*)(A32 + rc * KD + j0 + 64);
            float om = 1.f - theta;
            v[0] = theta * acc[i][0] + om * s0.x; v[1] = theta * acc[i][1] + om * s0.y;
            v[2] = theta * acc[i][2] + om * s0.z; v[3] = theta * acc[i][3] + om * s0.w;
            v[4] = theta * acc[i][4] + om * s1.x; v[5] = theta * acc[i][5] + om * s1.y;
            v[6] = theta * acc[i][6] + om * s1.z; v[7] = theta * acc[i][7] + om * s1.w;
#pragma unroll
            for (int c = 0; c < 8; c++) v[c] = v[c] > 0.f ? v[c] : 0.f;
        }
        float sum = 0.f, sq = 0.f;
#pragma unroll
        for (int c = 0; c < 8; c++) { sum += v[c]; sq += v[c] * v[c]; }
        sum += __shfl_xor(sum, 1); sum += __shfl_xor(sum, 2);
        sum += __shfl_xor(sum, 4); sum += __shfl_xor(sum, 8);
        sq  += __shfl_xor(sq, 1);  sq  += __shfl_xor(sq, 2);
        sq  += __shfl_xor(sq, 4);  sq  += __shfl_xor(sq, 8);
        float mu  = sum * (1.f / 128.f);
        float var = fmaxf(sq * (1.f / 128.f) - mu * mu, 0.f);
        float rs  = rsqrtf(var + LN_EPS);
        if (rg < N_NODES) {
            float4 o0, o1;
            o0.x = gm0.x * (v[0] - mu) * rs + be0.x;
            o0.y = gm0.y * (v[1] - mu) * rs + be0.y;
            o0.z = gm0.z * (v[2] - mu) * rs + be0.z;
            o0.w = gm0.w * (v[3] - mu) * rs + be0.w;
            o1.x = gm1.x * (v[4] - mu) * rs + be1.x;
            o1.y = gm1.y * (v[5] - mu) * rs + be1.y;
            o1.z = gm1.z * (v[6] - mu) * rs + be1.z;
            o1.w = gm1.w * (v[7] - mu) * rs + be1.w;
            float* dst = Hout + rg * 128;
            *(float4*)(dst + j0)      = o0;
            *(float4*)(dst + j0 + 64) = o1;
        }
    }
}

// ---------------- classifier (fp32 in, dtype-flag out) ----------------

__global__ __launch_bounds__(256) void k_cls(const float* __restrict__ H,
                                             const float* __restrict__ Wc,
                                             const float* __restrict__ bc,
                                             const int* __restrict__ flag,
                                             void* __restrict__ out) {
    __shared__ float wS[128][8];
    int tid = threadIdx.x;
    for (int idx = tid; idx < 128 * 7; idx += 256) wS[idx / 7][idx % 7] = Wc[idx];
    __syncthreads();
    int isf32 = *flag;
    int gid = blockIdx.x * 256 + tid;
    int n = gid >> 3, j = gid & 7;
    if (n >= N_NODES || j >= OUT_DIM) return;
    const float4* hr = (const float4*)(H + (size_t)n * 128);
    float acc = bc[j];
#pragma unroll
    for (int k4 = 0; k4 < 32; k4++) {
        float4 h4 = hr[k4];
        acc += h4.x * wS[4 * k4][j]     + h4.y * wS[4 * k4 + 1][j]
             + h4.z * wS[4 * k4 + 2][j] + h4.w * wS[4 * k4 + 3][j];
    }
    size_t oi = (size_t)n * OUT_DIM + j;
    if (isf32) ((float*)out)[oi] = acc;
    else       ((uint16_t*)out)[oi] = f2bf(acc);
}

// ---------------- launch ----------------

extern "C" void kernel_launch(void* const* d_in, const int* in_sizes, int n_in,
                              void* d_out, int out_size, void* d_ws, size_t ws_size,
                              hipStream_t stream) {
    const void* x_raw = d_in[0];
    const int*  ei    = (const int*)d_in[1];
    const int* row = ei;
    const int* col = ei + N_EDGES;

    char* ws = (char*)d_ws;
    size_t off = 0;
    auto alloc = [&](size_t b) { void* p = ws + off; off = (off + b + 255) & ~(size_t)255; return p; };
    int*   flag = (int*)alloc(4);
    float* stgf = (float*)alloc((size_t)99744 * 4);
    int*   deg  = (int*)alloc((size_t)N_NODES * 4);
    int*   rp   = (int*)alloc(((size_t)N_NODES + 1) * 4);
    int*   cur  = (int*)alloc((size_t)N_NODES * 4);
    float* dis  = (float*)alloc((size_t)N_NODES * 4);
    int*   incl = (int*)alloc((size_t)N_NODES * 4);
    int*   bsum = (int*)alloc((size_t)SCAN_NB * 4);
    int*   boff = (int*)alloc((size_t)SCAN_NB * 4);
    int*   csr  = (int*)alloc((size_t)N_EDGES * 4);
    float* h0   = (float*)alloc((size_t)N_NODES * HID * 4);
    float* h    = (float*)alloc((size_t)N_NODES * HID * 4);
    float* sup  = (float*)alloc((size_t)N_NODES * HID * 4);

    const float* Wp  = stgf + 0;
    const float* bp  = stgf + 32768;
    const float* gm  = stgf + 32896;
    const float* bt  = stgf + 33024;
    const float* qw  = stgf + 33152;
    const float* qb  = stgf + 33280;
    const float* cw  = stgf + 33296;
    const float* clw = stgf + 98832;
    const float* clb = stgf + 99728;

    k_detect<<<1, 64, 0, stream>>>((const uint32_t*)d_in[2], flag);
    k_cvt<<<(99720 + 255) / 256, 256, 0, stream>>>(d_in[2], d_in[3], d_in[4], d_in[5], d_in[6],
                                                   d_in[7], d_in[8], d_in[9], d_in[10], stgf, flag);

    hipMemsetAsync(deg, 0, (size_t)N_NODES * 4, stream);
    k_deg<<<(N_EDGES + 255) / 256, 256, 0, stream>>>(row, deg);
    k_scan1<<<SCAN_NB, SCAN_B, 0, stream>>>(deg, incl, bsum);
    k_scan2<<<1, 128, 0, stream>>>(bsum, boff);
    k_scan3<<<(N_NODES + 255) / 256, 256, 0, stream>>>(deg, incl, boff, rp, cur, dis);
    k_scatter<<<(N_EDGES + 255) / 256, 256, 0, stream>>>(row, col, cur, csr);

    const int gemm_grid = (N_NODES + 63) / 64;   // 1563
    k_gemm_ln<IN_DIM, 0><<<gemm_grid, 256, 0, stream>>>(x_raw, Wp, bp, gm, bt, 0.f, flag, h0);

    const float* hin = h0;
    for (int i = 0; i < N_LAYERS; i++) {
        k_spmm<<<(N_NODES + 3) / 4, 256, 0, stream>>>(hin, h0, rp, csr, dis, qw, qb, sup);
        float theta = 0.5f / (float)(i + 1);
        k_gemm_ln<HID, 1><<<gemm_grid, 256, 0, stream>>>(sup, cw + (size_t)i * HID * HID,
                                                         nullptr, gm, bt, theta, flag, h);
        hin = h;
    }
    k_cls<<<((size_t)N_NODES * 8 + 255) / 256, 256, 0, stream>>>(h, clw, clb, flag, d_out);
}

// Round 9
// 998.677 us; speedup vs baseline: 1.6019x; 1.2046x over previous
//
#include <hip/hip_runtime.h>
#include <hip/hip_bf16.h>
#include <hip/hip_fp16.h>
#include <stdint.h>

#define N_NODES 100000
#define N_EDGES 1600000
#define IN_DIM 256
#define HID 128
#define N_LAYERS 4
#define OUT_DIM 7
#define LN_EPS 1e-5f

#define SCAN_B 1024
#define SCAN_NB ((N_NODES + SCAN_B - 1) / SCAN_B)   // 98

__device__ inline float bf2f1(uint16_t u) {
    union { uint32_t i; float f; } a; a.i = ((uint32_t)u) << 16; return a.f;
}
__device__ inline uint16_t f2bf(float f) {
    union { float f; uint32_t i; } a; a.f = f;
    uint32_t lsb = (a.i >> 16) & 1u;
    a.i += 0x7fffu + lsb;          // round-to-nearest-even
    return (uint16_t)(a.i >> 16);
}
__device__ inline uint32_t packq(float a, float b, float qinv) {
    int qa = __float2int_rn(a * qinv);
    int qb = __float2int_rn(b * qinv);
    return ((uint32_t)(uint16_t)(short)qa) | (((uint32_t)(uint16_t)(short)qb) << 16);
}

// ---------------- dtype detection ----------------
__global__ void k_detect(const uint32_t* __restrict__ W, int* __restrict__ flag) {
    if (threadIdx.x == 0 && blockIdx.x == 0) {
        int cnt = 0;
        for (int i = 0; i < 64; i++) {
            uint32_t lo = W[i] & 0xffffu;
            uint32_t ex = (lo >> 7) & 0xff;
            if (ex >= 0x60 && ex < 0x7c) cnt++;
        }
        *flag = (cnt < 32) ? 1 : 0;   // 1 = fp32 inputs, 0 = bf16 inputs
    }
}

// ---------------- weight canonicalization (all weights -> fp32 staged) ----------------
__global__ __launch_bounds__(256) void k_cvt(const void* a0, const void* a1, const void* a2,
                                             const void* a3, const void* a4, const void* a5,
                                             const void* a6, const void* a7, const void* a8,
                                             float* __restrict__ dst, const int* __restrict__ flag) {
    int t = blockIdx.x * 256 + threadIdx.x;
    if (t >= 99720) return;
    const void* src; int i; int off;
    if      (t < 32768) { src = a0; i = t;         off = 0;     }   // W_proj 256x128
    else if (t < 32896) { src = a1; i = t - 32768; off = 32768; }   // b_proj 128
    else if (t < 33024) { src = a2; i = t - 32896; off = 32896; }   // gamma 128
    else if (t < 33152) { src = a3; i = t - 33024; off = 33024; }   // beta 128
    else if (t < 33280) { src = a4; i = t - 33152; off = 33152; }   // q_w 128
    else if (t < 33281) { src = a5; i = t - 33280; off = 33280; }   // q_b 1
    else if (t < 98817) { src = a6; i = t - 33281; off = 33296; }   // conv_w 4x128x128
    else if (t < 99713) { src = a7; i = t - 98817; off = 98832; }   // cls_w 128x7
    else                { src = a8; i = t - 99713; off = 99728; }   // cls_b 7
    float v;
    if (*flag) v = ((const float*)src)[i];
    else       v = bf2f1(((const uint16_t*)src)[i]);
    dst[off + i] = v;
}

// ---------------- graph prep ----------------

__global__ __launch_bounds__(256) void k_deg(const int* __restrict__ row, int* __restrict__ deg) {
    int e = blockIdx.x * 256 + threadIdx.x;
    if (e < N_EDGES) atomicAdd(&deg[row[e]], 1);
}

__global__ __launch_bounds__(SCAN_B) void k_scan1(const int* __restrict__ deg,
                                                  int* __restrict__ incl, int* __restrict__ bsum) {
    __shared__ int sm[SCAN_B];
    int t = threadIdx.x;
    int i = blockIdx.x * SCAN_B + t;
    int v = (i < N_NODES) ? deg[i] : 0;
    sm[t] = v;
    __syncthreads();
    for (int off = 1; off < SCAN_B; off <<= 1) {
        int add = (t >= off) ? sm[t - off] : 0;
        __syncthreads();
        sm[t] += add;
        __syncthreads();
    }
    if (i < N_NODES) incl[i] = sm[t];
    if (t == SCAN_B - 1) bsum[blockIdx.x] = sm[t];
}

__global__ __launch_bounds__(128) void k_scan2(const int* __restrict__ bsum, int* __restrict__ boff) {
    __shared__ int s[SCAN_NB];
    int t = threadIdx.x;
    if (t < SCAN_NB) s[t] = bsum[t];
    __syncthreads();
    if (t == 0) {
        int run = 0;
        for (int b = 0; b < SCAN_NB; b++) { int v = s[b]; s[b] = run; run += v; }
    }
    __syncthreads();
    if (t < SCAN_NB) boff[t] = s[t];
}

__global__ __launch_bounds__(256) void k_scan3(const int* __restrict__ deg, const int* __restrict__ incl,
                                               const int* __restrict__ boff,
                                               int* __restrict__ rp, int* __restrict__ cur,
                                               float* __restrict__ dis) {
    int i = blockIdx.x * 256 + threadIdx.x;
    if (i >= N_NODES) return;
    int d = deg[i];
    int excl = boff[i / SCAN_B] + incl[i] - d;
    rp[i]  = excl;
    cur[i] = excl;
    if (i == N_NODES - 1) rp[N_NODES] = excl + d;
    dis[i] = rsqrtf((float)(d > 0 ? d : 1));
}

// scatter edges into CSR as (col, ew) pairs; ew = dis[row]*dis[col] (full weight)
__global__ __launch_bounds__(256) void k_scatter(const int* __restrict__ row, const int* __restrict__ col,
                                                 int* __restrict__ cur, const float* __restrict__ dis,
                                                 int2* __restrict__ ed) {
    int e = blockIdx.x * 256 + threadIdx.x;
    if (e < N_EDGES) {
        int r = row[e], c = col[e];
        int pos = atomicAdd(&cur[r], 1);
        ed[pos] = make_int2(c, __float_as_int(dis[r] * dis[c]));
    }
}

// ---------------- fused SpMM + blend ----------------
// one wave per node; lane holds cols {2*lane, 2*lane+1}.
// Gathers use the per-row int16-quantized mirror Hq (+ per-row scale Sc).
// Gate s precomputed (fp32-exact) by the producing GEMM epilogue.

__global__ __launch_bounds__(256) void k_spmm(const uint32_t* __restrict__ Hq,
                                              const float* __restrict__ Sc,
                                              const float* __restrict__ H0,
                                              const int* __restrict__ rp,
                                              const int2* __restrict__ ed,
                                              const float* __restrict__ S,
                                              float* __restrict__ Sup) {
    int wid  = (blockIdx.x * 256 + threadIdx.x) >> 6;
    int lane = threadIdx.x & 63;
    if (wid >= N_NODES) return;

    float s = S[wid];

    int p0 = rp[wid], p1 = rp[wid + 1];
    float ax = 0.f, ay = 0.f;
    int p = p0;
    for (; p + 4 <= p1; p += 4) {
        int2 e0 = ed[p], e1 = ed[p + 1], e2 = ed[p + 2], e3 = ed[p + 3];
        uint32_t u0 = Hq[(size_t)e0.x * 64 + lane];
        uint32_t u1 = Hq[(size_t)e1.x * 64 + lane];
        uint32_t u2 = Hq[(size_t)e2.x * 64 + lane];
        uint32_t u3 = Hq[(size_t)e3.x * 64 + lane];
        float w0 = __int_as_float(e0.y) * Sc[e0.x];
        float w1 = __int_as_float(e1.y) * Sc[e1.x];
        float w2 = __int_as_float(e2.y) * Sc[e2.x];
        float w3 = __int_as_float(e3.y) * Sc[e3.x];
        ax += w0 * (float)((int)(u0 << 16) >> 16) + w1 * (float)((int)(u1 << 16) >> 16)
            + w2 * (float)((int)(u2 << 16) >> 16) + w3 * (float)((int)(u3 << 16) >> 16);
        ay += w0 * (float)((int)u0 >> 16) + w1 * (float)((int)u1 >> 16)
            + w2 * (float)((int)u2 >> 16) + w3 * (float)((int)u3 >> 16);
    }
    for (; p < p1; p++) {
        int2 e = ed[p];
        uint32_t u = Hq[(size_t)e.x * 64 + lane];
        float w = __int_as_float(e.y) * Sc[e.x];
        ax += w * (float)((int)(u << 16) >> 16);
        ay += w * (float)((int)u >> 16);
    }
    float2 h0v = ((const float2*)(H0 + (size_t)wid * 128))[lane];
    float oms = 1.f - s;
    float2 o;
    o.x = oms * ax + s * h0v.x;
    o.y = oms * ay + s * h0v.y;
    ((float2*)(Sup + (size_t)wid * 128))[lane] = o;
}

// ---------------- VALU fp32 GEMM, register-blocked 4x8, + fused LN + gate + quant ----
// Block = 64 rows x 128 cols, 256 threads.
// MODE 0: A = x (fp32 or bf16 per flag); out = LN(acc + bias)
// MODE 1: A = sup (fp32);                out = LN(relu(theta*acc + (1-theta)*A))
// Writes Hout (fp32) + Hq/Sc (per-row int16 mirror) + S (gate sigmoid, fp32-exact).

template <int KD, int MODE>
__global__ __launch_bounds__(256) void k_gemm_ln(const void* __restrict__ Araw,  // [N][KD]
                                                 const float* __restrict__ Wf,   // [KD][128] fp32
                                                 const float* __restrict__ bias,
                                                 const float* __restrict__ gamma,
                                                 const float* __restrict__ beta,
                                                 const float* __restrict__ qw,
                                                 const float* __restrict__ qb,
                                                 float theta, const int* __restrict__ flag,
                                                 float* __restrict__ Hout,       // [N][128] fp32
                                                 uint32_t* __restrict__ Hq,      // [N][64] int16x2
                                                 float* __restrict__ Sc,         // [N] quant scale
                                                 float* __restrict__ S) {        // [N] gate
    __shared__ float Ws[64][128];   // 32 KiB
    __shared__ float As[64][68];    // 17 KiB

    const int tid = threadIdx.x;
    const int cg = tid & 15, rr = tid >> 4;
    const int j0 = cg * 4;
    const size_t row0base = (size_t)blockIdx.x * 64;
    const size_t row0 = row0base + (size_t)rr * 4;
    const int f32in = (MODE == 0) ? *flag : 1;

    float acc[4][8];
#pragma unroll
    for (int i = 0; i < 4; i++)
#pragma unroll
        for (int c = 0; c < 8; c++) acc[i][c] = 0.f;

    for (int kh = 0; kh < KD / 64; kh++) {
        __syncthreads();
        const float* Wsrc = Wf + (size_t)kh * 64 * 128;
        for (int idx = tid * 4; idx < 64 * 128; idx += 1024)
            *(float4*)&Ws[idx >> 7][idx & 127] = *(const float4*)(Wsrc + idx);
#pragma unroll
        for (int qq = 0; qq < 4; qq++) {
            int idx4 = tid + qq * 256;
            int r = idx4 >> 4, c4 = idx4 & 15;
            size_t rg = row0base + r; if (rg >= N_NODES) rg = N_NODES - 1;
            float4 f;
            if (f32in) {
                f = *(const float4*)((const float*)Araw + rg * KD + kh * 64 + c4 * 4);
            } else {
                const uint16_t* p = (const uint16_t*)Araw + rg * KD + kh * 64 + c4 * 4;
                f.x = bf2f1(p[0]); f.y = bf2f1(p[1]); f.z = bf2f1(p[2]); f.w = bf2f1(p[3]);
            }
            *(float4*)&As[r][c4 * 4] = f;
        }
        __syncthreads();

#pragma unroll 4
        for (int k4 = 0; k4 < 16; k4++) {
            float4 av[4];
#pragma unroll
            for (int i = 0; i < 4; i++) av[i] = *(const float4*)&As[rr * 4 + i][k4 * 4];
#pragma unroll
            for (int kk = 0; kk < 4; kk++) {
                int k = k4 * 4 + kk;
                float4 w0 = *(const float4*)&Ws[k][j0];
                float4 w1 = *(const float4*)&Ws[k][j0 + 64];
#pragma unroll
                for (int i = 0; i < 4; i++) {
                    float a = (kk == 0) ? av[i].x : (kk == 1) ? av[i].y
                            : (kk == 2) ? av[i].z : av[i].w;
                    acc[i][0] += a * w0.x; acc[i][1] += a * w0.y;
                    acc[i][2] += a * w0.z; acc[i][3] += a * w0.w;
                    acc[i][4] += a * w1.x; acc[i][5] += a * w1.y;
                    acc[i][6] += a * w1.z; acc[i][7] += a * w1.w;
                }
            }
        }
    }

    float4 gm0 = *(const float4*)(gamma + j0), gm1 = *(const float4*)(gamma + j0 + 64);
    float4 be0 = *(const float4*)(beta  + j0), be1 = *(const float4*)(beta  + j0 + 64);
    float4 qw0 = *(const float4*)(qw + j0),   qw1 = *(const float4*)(qw + j0 + 64);
    const float qbv = qb[0];
    float4 bi0 = {0,0,0,0}, bi1 = {0,0,0,0};
    if (MODE == 0) { bi0 = *(const float4*)(bias + j0); bi1 = *(const float4*)(bias + j0 + 64); }

#pragma unroll
    for (int i = 0; i < 4; i++) {
        size_t rg = row0 + i;
        size_t rc = (rg < N_NODES) ? rg : (N_NODES - 1);
        float v[8];
        if (MODE == 0) {
            v[0] = acc[i][0] + bi0.x; v[1] = acc[i][1] + bi0.y;
            v[2] = acc[i][2] + bi0.z; v[3] = acc[i][3] + bi0.w;
            v[4] = acc[i][4] + bi1.x; v[5] = acc[i][5] + bi1.y;
            v[6] = acc[i][6] + bi1.z; v[7] = acc[i][7] + bi1.w;
        } else {
            const float* Ar = (const float*)Araw + rc * KD;
            float4 s0 = *(const float4*)(Ar + j0);
            float4 s1 = *(const float4*)(Ar + j0 + 64);
            float om = 1.f - theta;
            v[0] = theta * acc[i][0] + om * s0.x; v[1] = theta * acc[i][1] + om * s0.y;
            v[2] = theta * acc[i][2] + om * s0.z; v[3] = theta * acc[i][3] + om * s0.w;
            v[4] = theta * acc[i][4] + om * s1.x; v[5] = theta * acc[i][5] + om * s1.y;
            v[6] = theta * acc[i][6] + om * s1.z; v[7] = theta * acc[i][7] + om * s1.w;
#pragma unroll
            for (int c = 0; c < 8; c++) v[c] = v[c] > 0.f ? v[c] : 0.f;
        }
        float sum = 0.f, sq = 0.f;
#pragma unroll
        for (int c = 0; c < 8; c++) { sum += v[c]; sq += v[c] * v[c]; }
        sum += __shfl_xor(sum, 1); sum += __shfl_xor(sum, 2);
        sum += __shfl_xor(sum, 4); sum += __shfl_xor(sum, 8);
        sq  += __shfl_xor(sq, 1);  sq  += __shfl_xor(sq, 2);
        sq  += __shfl_xor(sq, 4);  sq  += __shfl_xor(sq, 8);
        float mu  = sum * (1.f / 128.f);
        float var = fmaxf(sq * (1.f / 128.f) - mu * mu, 0.f);
        float rs  = rsqrtf(var + LN_EPS);

        float y[8];
        y[0] = gm0.x * (v[0] - mu) * rs + be0.x;
        y[1] = gm0.y * (v[1] - mu) * rs + be0.y;
        y[2] = gm0.z * (v[2] - mu) * rs + be0.z;
        y[3] = gm0.w * (v[3] - mu) * rs + be0.w;
        y[4] = gm1.x * (v[4] - mu) * rs + be1.x;
        y[5] = gm1.y * (v[5] - mu) * rs + be1.y;
        y[6] = gm1.z * (v[6] - mu) * rs + be1.z;
        y[7] = gm1.w * (v[7] - mu) * rs + be1.w;

        // gate dot (fp32-exact h in registers)
        float zd = y[0] * qw0.x + y[1] * qw0.y + y[2] * qw0.z + y[3] * qw0.w
                 + y[4] * qw1.x + y[5] * qw1.y + y[6] * qw1.z + y[7] * qw1.w;
        zd += __shfl_xor(zd, 1); zd += __shfl_xor(zd, 2);
        zd += __shfl_xor(zd, 4); zd += __shfl_xor(zd, 8);

        // per-row absmax for int16 quant
        float am = 0.f;
#pragma unroll
        for (int c = 0; c < 8; c++) am = fmaxf(am, fabsf(y[c]));
        am = fmaxf(am, __shfl_xor(am, 1)); am = fmaxf(am, __shfl_xor(am, 2));
        am = fmaxf(am, __shfl_xor(am, 4)); am = fmaxf(am, __shfl_xor(am, 8));
        float qsc  = fmaxf(am, 1e-20f) * (1.f / 32767.f);
        float qinv = 32767.f / fmaxf(am, 1e-20f);

        if (rg < N_NODES) {
            float* dst = Hout + rg * 128;
            *(float4*)(dst + j0)      = *(float4*)&y[0];
            *(float4*)(dst + j0 + 64) = *(float4*)&y[4];
            uint32_t* mq = Hq + rg * 64;
            mq[j0 / 2]          = packq(y[0], y[1], qinv);
            mq[j0 / 2 + 1]      = packq(y[2], y[3], qinv);
            mq[32 + j0 / 2]     = packq(y[4], y[5], qinv);
            mq[32 + j0 / 2 + 1] = packq(y[6], y[7], qinv);
            if (cg == 0) {
                Sc[rg] = qsc;
                S[rg]  = 1.f / (1.f + __expf(-(zd + qbv - 1.f)));
            }
        }
    }
}

// ---------------- classifier (fp32 in, dtype-flag out) ----------------

__global__ __launch_bounds__(256) void k_cls(const float* __restrict__ H,
                                             const float* __restrict__ Wc,
                                             const float* __restrict__ bc,
                                             const int* __restrict__ flag,
                                             void* __restrict__ out) {
    __shared__ float wS[128][8];
    int tid = threadIdx.x;
    for (int idx = tid; idx < 128 * 7; idx += 256) wS[idx / 7][idx % 7] = Wc[idx];
    __syncthreads();
    int isf32 = *flag;
    int gid = blockIdx.x * 256 + tid;
    int n = gid >> 3, j = gid & 7;
    if (n >= N_NODES || j >= OUT_DIM) return;
    const float4* hr = (const float4*)(H + (size_t)n * 128);
    float acc = bc[j];
#pragma unroll
    for (int k4 = 0; k4 < 32; k4++) {
        float4 h4 = hr[k4];
        acc += h4.x * wS[4 * k4][j]     + h4.y * wS[4 * k4 + 1][j]
             + h4.z * wS[4 * k4 + 2][j] + h4.w * wS[4 * k4 + 3][j];
    }
    size_t oi = (size_t)n * OUT_DIM + j;
    if (isf32) ((float*)out)[oi] = acc;
    else       ((uint16_t*)out)[oi] = f2bf(acc);
}

// ---------------- launch ----------------

extern "C" void kernel_launch(void* const* d_in, const int* in_sizes, int n_in,
                              void* d_out, int out_size, void* d_ws, size_t ws_size,
                              hipStream_t stream) {
    const void* x_raw = d_in[0];
    const int*  ei    = (const int*)d_in[1];
    const int* row = ei;
    const int* col = ei + N_EDGES;

    char* ws = (char*)d_ws;
    size_t off = 0;
    auto alloc = [&](size_t b) { void* p = ws + off; off = (off + b + 255) & ~(size_t)255; return p; };
    int*      flag = (int*)alloc(4);
    float*    stgf = (float*)alloc((size_t)99744 * 4);
    int*      deg  = (int*)alloc((size_t)N_NODES * 4);
    int*      rp   = (int*)alloc(((size_t)N_NODES + 1) * 4);
    int*      cur  = (int*)alloc((size_t)N_NODES * 4);
    float*    dis  = (float*)alloc((size_t)N_NODES * 4);
    int*      incl = (int*)alloc((size_t)N_NODES * 4);
    int*      bsum = (int*)alloc((size_t)SCAN_NB * 4);
    int*      boff = (int*)alloc((size_t)SCAN_NB * 4);
    int2*     ed   = (int2*)alloc((size_t)N_EDGES * 8);
    float*    h0   = (float*)alloc((size_t)N_NODES * HID * 4);
    float*    h    = (float*)alloc((size_t)N_NODES * HID * 4);
    float*    sup  = (float*)alloc((size_t)N_NODES * HID * 4);
    uint32_t* hq   = (uint32_t*)alloc((size_t)N_NODES * 64 * 4);  // int16 mirror
    float*    Scq  = (float*)alloc((size_t)N_NODES * 4);          // quant scales
    float*    Sg   = (float*)alloc((size_t)N_NODES * 4);          // gate sigmoid

    const float* Wp  = stgf + 0;
    const float* bp  = stgf + 32768;
    const float* gm  = stgf + 32896;
    const float* bt  = stgf + 33024;
    const float* qw  = stgf + 33152;
    const float* qb  = stgf + 33280;
    const float* cw  = stgf + 33296;
    const float* clw = stgf + 98832;
    const float* clb = stgf + 99728;

    k_detect<<<1, 64, 0, stream>>>((const uint32_t*)d_in[2], flag);
    k_cvt<<<(99720 + 255) / 256, 256, 0, stream>>>(d_in[2], d_in[3], d_in[4], d_in[5], d_in[6],
                                                   d_in[7], d_in[8], d_in[9], d_in[10], stgf, flag);

    hipMemsetAsync(deg, 0, (size_t)N_NODES * 4, stream);
    k_deg<<<(N_EDGES + 255) / 256, 256, 0, stream>>>(row, deg);
    k_scan1<<<SCAN_NB, SCAN_B, 0, stream>>>(deg, incl, bsum);
    k_scan2<<<1, 128, 0, stream>>>(bsum, boff);
    k_scan3<<<(N_NODES + 255) / 256, 256, 0, stream>>>(deg, incl, boff, rp, cur, dis);
    k_scatter<<<(N_EDGES + 255) / 256, 256, 0, stream>>>(row, col, cur, dis, ed);

    const int gemm_grid = (N_NODES + 63) / 64;   // 1563
    k_gemm_ln<IN_DIM, 0><<<gemm_grid, 256, 0, stream>>>(x_raw, Wp, bp, gm, bt, qw, qb,
                                                        0.f, flag, h0, hq, Scq, Sg);

    for (int i = 0; i < N_LAYERS; i++) {
        k_spmm<<<(N_NODES + 3) / 4, 256, 0, stream>>>(hq, Scq, h0, rp, ed, Sg, sup);
        float theta = 0.5f / (float)(i + 1);
        k_gemm_ln<HID, 1><<<gemm_grid, 256, 0, stream>>>(sup, cw + (size_t)i * HID * HID,
                                                         nullptr, gm, bt, qw, qb,
                                                         theta, flag, h, hq, Scq, Sg);
    }
    k_cls<<<((size_t)N_NODES * 8 + 255) / 256, 256, 0, stream>>>(h, clw, clb, flag, d_out);
}